// Round 1
// baseline (186.491 us; speedup 1.0000x reference)
//
#include <hip/hip_runtime.h>

#define NP 8192
#define KMAX 32
#define LK 0.01f
#define EPSBN 1e-5f
#define QPB 4

static constexpr int O_OUT = NP * 64;          // 524288
static constexpr int O_POS = O_OUT + NP * 3;   // 548864
static constexpr int O_BAT = O_POS + NP;       // 557056
static constexpr int O_RFL = O_BAT + NP;       // 565248
static constexpr int O_TOT = O_RFL + 4;        // 565252

// order-preserving float<->uint mapping for atomic max/min
__device__ __forceinline__ unsigned enc_f(float f) {
    unsigned u = __float_as_uint(f);
    return (u & 0x80000000u) ? ~u : (u | 0x80000000u);
}
__device__ __forceinline__ float dec_f(unsigned e) {
    unsigned u = (e & 0x80000000u) ? (e & 0x7fffffffu) : ~e;
    return __uint_as_float(u);
}

// ---------------- K0: batch conversion (int32 vs int64 detect), ranges, |pos|^2
__global__ __launch_bounds__(1024) void k0_setup(const int* __restrict__ braw,
                                                 const float* __restrict__ pos,
                                                 int* __restrict__ bati,
                                                 int* __restrict__ bstart,
                                                 float* __restrict__ sqv) {
    __shared__ int flag;
    __shared__ int hist[4];
    int t = threadIdx.x;
    if (t == 0) flag = 0;
    if (t < 4) hist[t] = 0;
    __syncthreads();
    // If data is really int64 (little-endian), int32 view is [v0,0,v1,0,...]
    // which violates sorted/non-negative-range as soon as any v>0 appears.
    for (int i = t; i < NP; i += 1024) {
        int v = braw[i];
        bool bad = (v < 0) || (v > 3);
        if (i > 0 && braw[i - 1] > v) bad = true;
        if (bad) flag = 1;
    }
    __syncthreads();
    const int is64 = flag;
    for (int i = t; i < NP; i += 1024) {
        int v = is64 ? braw[2 * i] : braw[i];
        v = v < 0 ? 0 : (v > 3 ? 3 : v);
        bati[i] = v;
        atomicAdd(&hist[v], 1);
        float px = pos[3 * i], py = pos[3 * i + 1], pz = pos[3 * i + 2];
        sqv[i] = px * px + py * py + pz * pz;
    }
    __syncthreads();
    if (t == 0) {
        int acc = 0;
        for (int b = 0; b < 4; b++) { bstart[b] = acc; acc += hist[b]; }
        bstart[4] = acc;
    }
}

// ---------------- K1: radius search within batch segment, emit edge list
__global__ __launch_bounds__(256) void k1_nbr(const float* __restrict__ pos,
                                              const float* __restrict__ sqv,
                                              const int* __restrict__ bati,
                                              const int* __restrict__ bstart,
                                              int* __restrict__ ecnt,
                                              int* __restrict__ ei,
                                              int* __restrict__ ej) {
    __shared__ int lcnt[QPB];
    __shared__ int base_s[QPB];
    __shared__ int cidx[QPB][256];
    __shared__ float cd2[QPB][256];
    constexpr float R2C = (float)((0.02 * 2.1) * (0.02 * 2.1));
    int t = threadIdx.x;
    int i0 = blockIdx.x * QPB;
    if (t < QPB) lcnt[t] = 0;
    __syncthreads();
    float qx[QPB], qy[QPB], qz[QPB], qs[QPB];
    int ql[QPB], qh[QPB];
    int lo = NP, hi = 0;
#pragma unroll
    for (int q = 0; q < QPB; q++) {
        int i = i0 + q;
        qx[q] = pos[3 * i]; qy[q] = pos[3 * i + 1]; qz[q] = pos[3 * i + 2];
        qs[q] = sqv[i];
        int b = bati[i];
        ql[q] = bstart[b]; qh[q] = bstart[b + 1];
        lo = min(lo, ql[q]); hi = max(hi, qh[q]);
    }
    for (int j = lo + t; j < hi; j += 256) {
        float xj = pos[3 * j], yj = pos[3 * j + 1], zj = pos[3 * j + 2];
        float sj = sqv[j];
#pragma unroll
        for (int q = 0; q < QPB; q++) {
            if (j >= ql[q] && j < qh[q]) {
                float d2 = qs[q] + sj - 2.0f * (qx[q] * xj + qy[q] * yj + qz[q] * zj);
                if (d2 < R2C) {
                    int p = atomicAdd(&lcnt[q], 1);
                    if (p < 256) { cidx[q][p] = j; cd2[q][p] = d2; }
                }
            }
        }
    }
    __syncthreads();
    if (t < QPB) {  // rare overflow: exact nearest-KMAX selection, serial
        int q = t;
        int c = lcnt[q]; c = c > 256 ? 256 : c;
        if (c > KMAX) {
            for (int s = 0; s < KMAX; s++) {
                int bi = s; float bd = cd2[q][s];
                for (int r = s + 1; r < c; r++)
                    if (cd2[q][r] < bd) { bd = cd2[q][r]; bi = r; }
                float tf = cd2[q][s]; cd2[q][s] = cd2[q][bi]; cd2[q][bi] = tf;
                int ti = cidx[q][s]; cidx[q][s] = cidx[q][bi]; cidx[q][bi] = ti;
            }
            c = KMAX;
        }
        lcnt[q] = c;
        base_s[q] = atomicAdd(ecnt, c);
    }
    __syncthreads();
#pragma unroll
    for (int q = 0; q < QPB; q++) {
        int c = lcnt[q];
        if (t < c) { ei[base_s[q] + t] = i0 + q; ej[base_s[q] + t] = cidx[q][t]; }
    }
}

// ---------------- K2: wave-per-edge MLP; lane = channel; track max/min + BN sums
__global__ __launch_bounds__(256) void k2_mlp(const float* __restrict__ xin,
                                              const float* __restrict__ pos,
                                              const float* __restrict__ rfl,
                                              const float* __restrict__ sf,
                                              const float* __restrict__ w1,
                                              const float* __restrict__ b1,
                                              const float* __restrict__ w2,
                                              const float* __restrict__ b2,
                                              const int* __restrict__ bati,
                                              const int* __restrict__ ecnt,
                                              const int* __restrict__ ei,
                                              const int* __restrict__ ej,
                                              unsigned* __restrict__ umax,
                                              unsigned* __restrict__ umin,
                                              float* __restrict__ sums,
                                              float* __restrict__ sumsq) {
    __shared__ float4 h1b[4][16];
    __shared__ float red[256];
    int t = threadIdx.x;
    int lane = t & 63;
    int wid = __builtin_amdgcn_readfirstlane(t >> 6);  // wave-uniform SGPR
    float w1c[8];
#pragma unroll
    for (int f = 0; f < 8; f++) w1c[f] = w1[f * 64 + lane];
    float b1c = b1[lane];
    float4 w2c[16];
#pragma unroll
    for (int m = 0; m < 16; m++) {
        w2c[m].x = w2[(4 * m + 0) * 64 + lane];
        w2c[m].y = w2[(4 * m + 1) * 64 + lane];
        w2c[m].z = w2[(4 * m + 2) * 64 + lane];
        w2c[m].w = w2[(4 * m + 3) * 64 + lane];
    }
    float b2c = b2[lane];
    float ssum = 0.f, ssq = 0.f;
    const int E = ecnt[0];
    const int nw = gridDim.x * 4;
    for (int e = blockIdx.x * 4 + wid; e < E; e += nw) {
        int i = ei[e], j = ej[e];               // wave-uniform -> scalar loads
        float s = sf[bati[i]];
        float f0 = xin[4 * j + 0], f1 = xin[4 * j + 1];
        float f2 = xin[4 * j + 2], f3 = xin[4 * j + 3];
        float f4 = pos[3 * j + 0] / s - pos[3 * i + 0] / s;
        float f5 = pos[3 * j + 1] / s - pos[3 * i + 1] / s;
        float f6 = pos[3 * j + 2] / s - pos[3 * i + 2] / s;
        float f7 = rfl[j] - rfl[i];
        float a = b1c + f0 * w1c[0] + f1 * w1c[1] + f2 * w1c[2] + f3 * w1c[3]
                      + f4 * w1c[4] + f5 * w1c[5] + f6 * w1c[6] + f7 * w1c[7];
        float h1 = a > 0.f ? a : LK * a;
        ((float*)h1b[wid])[lane] = h1;          // intra-wave LDS exchange
        __threadfence_block();
        float acc = b2c;
#pragma unroll
        for (int m = 0; m < 16; m++) {
            float4 hv = h1b[wid][m];            // broadcast ds_read_b128
            acc += hv.x * w2c[m].x + hv.y * w2c[m].y + hv.z * w2c[m].z + hv.w * w2c[m].w;
        }
        float h2 = acc > 0.f ? acc : LK * acc;
        unsigned en = enc_f(h2);
        atomicMax(&umax[i * 64 + lane], en);
        atomicMin(&umin[i * 64 + lane], en);
        ssum += h2;
        ssq += h2 * h2;
    }
    red[t] = ssum;
    __syncthreads();
    if (t < 64) atomicAdd(&sums[t], red[t] + red[t + 64] + red[t + 128] + red[t + 192]);
    __syncthreads();
    red[t] = ssq;
    __syncthreads();
    if (t < 64) atomicAdd(&sumsq[t], red[t] + red[t + 64] + red[t + 128] + red[t + 192]);
}

// ---------------- K3: BN affine + max/min pick + tuple passthrough
__global__ __launch_bounds__(256) void k3_fin(const unsigned* __restrict__ umax,
                                              const unsigned* __restrict__ umin,
                                              const float* __restrict__ sums,
                                              const float* __restrict__ sumsq,
                                              const float* __restrict__ gamma,
                                              const float* __restrict__ beta,
                                              const int* __restrict__ ecnt,
                                              const float* __restrict__ pos,
                                              const int* __restrict__ bati,
                                              const float* __restrict__ rfl,
                                              const float* __restrict__ sf,
                                              float* __restrict__ out) {
    int t = blockIdx.x * 256 + threadIdx.x;
    if (t < O_OUT) {
        int c = t & 63;
        float cntf = (float)ecnt[0];
        float mean = sums[c] / cntf;
        float var = sumsq[c] / cntf - mean * mean;
        var = var > 0.f ? var : 0.f;
        float inv = 1.0f / sqrtf(var + EPSBN);
        float scl = gamma[c] * inv;
        float shf = beta[c] - mean * scl;
        float v = (scl >= 0.f) ? dec_f(umax[t]) : dec_f(umin[t]);
        out[t] = scl * v + shf;
    } else if (t < O_POS) {
        out[t] = pos[t - O_OUT];
    } else if (t < O_BAT) {
        out[t] = (float)bati[t - O_POS];
    } else if (t < O_RFL) {
        out[t] = rfl[t - O_BAT];
    } else if (t < O_TOT) {
        out[t] = sf[t - O_RFL];
    }
}

extern "C" void kernel_launch(void* const* d_in, const int* in_sizes, int n_in,
                              void* d_out, int out_size, void* d_ws, size_t ws_size,
                              hipStream_t stream) {
    const float* xin  = (const float*)d_in[0];
    const float* pos  = (const float*)d_in[1];
    const float* rfl  = (const float*)d_in[2];
    const float* sf   = (const float*)d_in[3];
    const float* w1   = (const float*)d_in[4];
    const float* b1   = (const float*)d_in[5];
    const float* w2   = (const float*)d_in[6];
    const float* b2   = (const float*)d_in[7];
    const float* gam  = (const float*)d_in[8];
    const float* bet  = (const float*)d_in[9];
    const int*   brw  = (const int*)d_in[10];
    float* out = (float*)d_out;

    char* ws = (char*)d_ws;
    // layout: [0] ecnt, [64] sums[64], [320] sumsq[64], [1024] umax 2MB,
    // [+2MB] umin 2MB, then edge_i 1MB, edge_j 1MB, bati 32KB, bstart, sqv 32KB
    int*      ecnt  = (int*)(ws + 0);
    float*    sums  = (float*)(ws + 64);
    float*    sumsq = (float*)(ws + 320);
    unsigned* umax  = (unsigned*)(ws + 1024);
    unsigned* umin  = (unsigned*)(ws + 1024 + 2097152);
    int*      ei    = (int*)(ws + 1024 + 2 * 2097152);
    int*      ej    = (int*)(ws + 1024 + 2 * 2097152 + 1048576);
    int*      bati  = (int*)(ws + 1024 + 2 * 2097152 + 2 * 1048576);
    int*      bstart= (int*)(ws + 1024 + 2 * 2097152 + 2 * 1048576 + 32768);
    float*    sqv   = (float*)(ws + 1024 + 2 * 2097152 + 2 * 1048576 + 32768 + 64);

    hipMemsetAsync(ws, 0, 1024, stream);                 // ecnt + sums + sumsq
    hipMemsetAsync(umax, 0x00, 2097152, stream);         // encoded -inf
    hipMemsetAsync(umin, 0xFF, 2097152, stream);         // encoded +inf

    k0_setup<<<1, 1024, 0, stream>>>(brw, pos, bati, bstart, sqv);
    k1_nbr<<<NP / QPB, 256, 0, stream>>>(pos, sqv, bati, bstart, ecnt, ei, ej);
    k2_mlp<<<1024, 256, 0, stream>>>(xin, pos, rfl, sf, w1, b1, w2, b2,
                                     bati, ecnt, ei, ej, umax, umin, sums, sumsq);
    k3_fin<<<(O_TOT + 255) / 256, 256, 0, stream>>>(umax, umin, sums, sumsq, gam, bet,
                                                    ecnt, pos, bati, rfl, sf, out);
}

// Round 2
// 160.235 us; speedup vs baseline: 1.1639x; 1.1639x over previous
//
#include <hip/hip_runtime.h>

#define NP 8192
#define NGROUP 2048          // NP/4 query groups
#define GRID12 512
#define KMAX 32
#define LK 0.01f
#define EPSBN 1e-5f

static constexpr int O_OUT = NP * 64;          // 524288
static constexpr int O_POS = O_OUT + NP * 3;   // 548864
static constexpr int O_BAT = O_POS + NP;       // 557056
static constexpr int O_RFL = O_BAT + NP;       // 565248
static constexpr int O_TOT = O_RFL + 4;        // 565252

// ---------------- K0: batch int64-vs-int32 detect, convert, segment starts
__global__ __launch_bounds__(1024) void k0_setup(const int* __restrict__ braw,
                                                 int* __restrict__ bati,
                                                 int* __restrict__ bstart) {
    __shared__ int flag;
    __shared__ int hist[4];
    int t = threadIdx.x;
    if (t == 0) flag = 0;
    if (t < 4) hist[t] = 0;
    __syncthreads();
    // int64 little-endian viewed as int32 is [v0,0,v1,0,...]: breaks sortedness
    // or range as soon as any v>0 exists.
    for (int i = t; i < NP; i += 1024) {
        int v = braw[i];
        bool bad = (v < 0) || (v > 3);
        if (i > 0 && braw[i - 1] > v) bad = true;
        if (bad) flag = 1;
    }
    __syncthreads();
    const int is64 = flag;
    for (int i = t; i < NP; i += 1024) {
        int v = is64 ? braw[2 * i] : braw[i];
        v = v < 0 ? 0 : (v > 3 ? 3 : v);
        bati[i] = v;
        atomicAdd(&hist[v], 1);
    }
    __syncthreads();
    if (t == 0) {
        int acc = 0;
        for (int b = 0; b < 4; b++) { bstart[b] = acc; acc += hist[b]; }
        bstart[4] = acc;
    }
}

// ---------------- K12: fused radius search + per-edge MLP + register max/min
// Block = 256 threads = 4 waves; group g = 4 queries; wave w owns query g*4+w.
__global__ __launch_bounds__(256) void k12_fused(const float* __restrict__ xin,
                                                 const float* __restrict__ pos,
                                                 const float* __restrict__ rfl,
                                                 const float* __restrict__ sf,
                                                 const float* __restrict__ w1,
                                                 const float* __restrict__ b1,
                                                 const float* __restrict__ w2,
                                                 const float* __restrict__ b2,
                                                 const int* __restrict__ bati,
                                                 const int* __restrict__ bstart,
                                                 float* __restrict__ vmaxg,
                                                 float* __restrict__ vming,
                                                 float* __restrict__ sums,
                                                 float* __restrict__ sumsq,
                                                 int* __restrict__ ecnt) {
    __shared__ int lcnt[4];
    __shared__ int cidx[4][256];
    __shared__ float cd2[4][256];
    __shared__ float4 h1b[4][16];
    __shared__ float red[256];
    __shared__ int ecount;
    constexpr float R2C = (float)((0.02 * 2.1) * (0.02 * 2.1));
    int t = threadIdx.x;
    int lane = t & 63;
    int w = t >> 6;
    // weights resident in registers; lane = output channel
    float w1c[8];
#pragma unroll
    for (int f = 0; f < 8; f++) w1c[f] = w1[f * 64 + lane];
    float b1c = b1[lane];
    float4 w2c[16];
#pragma unroll
    for (int m = 0; m < 16; m++) {
        w2c[m].x = w2[(4 * m + 0) * 64 + lane];
        w2c[m].y = w2[(4 * m + 1) * 64 + lane];
        w2c[m].z = w2[(4 * m + 2) * 64 + lane];
        w2c[m].w = w2[(4 * m + 3) * 64 + lane];
    }
    float b2c = b2[lane];
    if (t == 0) ecount = 0;
    float ssum = 0.f, ssq = 0.f;

    for (int g = blockIdx.x; g < NGROUP; g += GRID12) {
        __syncthreads();                 // protect LDS reuse from prior iter
        if (t < 4) lcnt[t] = 0;
        __syncthreads();
        int i0 = g * 4;
        // ---- phase 1: scan batch segment for 4 queries
        float qx[4], qy[4], qz[4], qs[4];
        int ql[4], qh[4];
        int lo = NP, hi = 0;
#pragma unroll
        for (int q = 0; q < 4; q++) {
            int i = i0 + q;
            qx[q] = pos[3 * i]; qy[q] = pos[3 * i + 1]; qz[q] = pos[3 * i + 2];
            qs[q] = qx[q] * qx[q] + qy[q] * qy[q] + qz[q] * qz[q];
            int b = bati[i];
            ql[q] = bstart[b]; qh[q] = bstart[b + 1];
            lo = min(lo, ql[q]); hi = max(hi, qh[q]);
        }
        for (int j = lo + t; j < hi; j += 256) {
            float xj = pos[3 * j], yj = pos[3 * j + 1], zj = pos[3 * j + 2];
            float sj = xj * xj + yj * yj + zj * zj;
#pragma unroll
            for (int q = 0; q < 4; q++) {
                if (j >= ql[q] && j < qh[q]) {
                    float d2 = qs[q] + sj - 2.0f * (qx[q] * xj + qy[q] * yj + qz[q] * zj);
                    if (d2 < R2C) {
                        int p = atomicAdd(&lcnt[q], 1);
                        if (p < 256) { cidx[q][p] = j; cd2[q][p] = d2; }
                    }
                }
            }
        }
        __syncthreads();
        if (t < 4) {                     // rare overflow: exact nearest-KMAX
            int c = lcnt[t]; c = c > 256 ? 256 : c;
            if (c > KMAX) {
                for (int s = 0; s < KMAX; s++) {
                    int bi = s; float bd = cd2[t][s];
                    for (int r = s + 1; r < c; r++)
                        if (cd2[t][r] < bd) { bd = cd2[t][r]; bi = r; }
                    float tf = cd2[t][s]; cd2[t][s] = cd2[t][bi]; cd2[t][bi] = tf;
                    int ti = cidx[t][s]; cidx[t][s] = cidx[t][bi]; cidx[t][bi] = ti;
                }
                c = KMAX;
            }
            lcnt[t] = c;
            atomicAdd(&ecount, c);
        }
        __syncthreads();
        // ---- phase 2: wave w runs MLP over query i0+w's edges, lane=channel
        {
            int i = i0 + w;
            int c = lcnt[w];
            float s = sf[bati[i]];
            float rs = 1.0f / s;
            float pxi = pos[3 * i] * rs, pyi = pos[3 * i + 1] * rs, pzi = pos[3 * i + 2] * rs;
            float ri = rfl[i];
            float vmax = -3.4e38f, vmin = 3.4e38f;
            for (int e = 0; e < c; e++) {
                int j = __builtin_amdgcn_readfirstlane(cidx[w][e]);  // wave-uniform
                float f0 = xin[4 * j + 0], f1 = xin[4 * j + 1];
                float f2 = xin[4 * j + 2], f3 = xin[4 * j + 3];
                float f4 = pos[3 * j + 0] * rs - pxi;
                float f5 = pos[3 * j + 1] * rs - pyi;
                float f6 = pos[3 * j + 2] * rs - pzi;
                float f7 = rfl[j] - ri;
                float a = b1c + f0 * w1c[0] + f1 * w1c[1] + f2 * w1c[2] + f3 * w1c[3]
                              + f4 * w1c[4] + f5 * w1c[5] + f6 * w1c[6] + f7 * w1c[7];
                float h1 = a > 0.f ? a : LK * a;
                ((float*)h1b[w])[lane] = h1;       // intra-wave LDS exchange
                __threadfence_block();
                float acc = b2c;
#pragma unroll
                for (int m = 0; m < 16; m++) {
                    float4 hv = h1b[w][m];         // broadcast ds_read_b128
                    acc += hv.x * w2c[m].x + hv.y * w2c[m].y + hv.z * w2c[m].z + hv.w * w2c[m].w;
                }
                float h2 = acc > 0.f ? acc : LK * acc;
                vmax = fmaxf(vmax, h2);
                vmin = fminf(vmin, h2);
                ssum += h2;
                ssq += h2 * h2;
            }
            vmaxg[i * 64 + lane] = vmax;           // c>=1 always (self edge)
            vming[i * 64 + lane] = vmin;
        }
    }
    // ---- BN stat reduction: one atomic set per block
    red[t] = ssum;
    __syncthreads();
    if (t < 64) atomicAdd(&sums[t], red[t] + red[t + 64] + red[t + 128] + red[t + 192]);
    __syncthreads();
    red[t] = ssq;
    __syncthreads();
    if (t < 64) atomicAdd(&sumsq[t], red[t] + red[t + 64] + red[t + 128] + red[t + 192]);
    if (t == 0) atomicAdd(ecnt, ecount);
}

// ---------------- K3: BN affine + max/min pick + tuple passthrough
__global__ __launch_bounds__(256) void k3_fin(const float* __restrict__ vmaxg,
                                              const float* __restrict__ vming,
                                              const float* __restrict__ sums,
                                              const float* __restrict__ sumsq,
                                              const float* __restrict__ gamma,
                                              const float* __restrict__ beta,
                                              const int* __restrict__ ecnt,
                                              const float* __restrict__ pos,
                                              const int* __restrict__ bati,
                                              const float* __restrict__ rfl,
                                              const float* __restrict__ sf,
                                              float* __restrict__ out) {
    int t = blockIdx.x * 256 + threadIdx.x;
    if (t < O_OUT) {
        int c = t & 63;
        float cntf = (float)ecnt[0];
        float mean = sums[c] / cntf;
        float var = sumsq[c] / cntf - mean * mean;
        var = var > 0.f ? var : 0.f;
        float inv = 1.0f / sqrtf(var + EPSBN);
        float scl = gamma[c] * inv;
        float shf = beta[c] - mean * scl;
        float v = (scl >= 0.f) ? vmaxg[t] : vming[t];
        out[t] = scl * v + shf;
    } else if (t < O_POS) {
        out[t] = pos[t - O_OUT];
    } else if (t < O_BAT) {
        out[t] = (float)bati[t - O_POS];
    } else if (t < O_RFL) {
        out[t] = rfl[t - O_BAT];
    } else if (t < O_TOT) {
        out[t] = sf[t - O_RFL];
    }
}

extern "C" void kernel_launch(void* const* d_in, const int* in_sizes, int n_in,
                              void* d_out, int out_size, void* d_ws, size_t ws_size,
                              hipStream_t stream) {
    const float* xin  = (const float*)d_in[0];
    const float* pos  = (const float*)d_in[1];
    const float* rfl  = (const float*)d_in[2];
    const float* sf   = (const float*)d_in[3];
    const float* w1   = (const float*)d_in[4];
    const float* b1   = (const float*)d_in[5];
    const float* w2   = (const float*)d_in[6];
    const float* b2   = (const float*)d_in[7];
    const float* gam  = (const float*)d_in[8];
    const float* bet  = (const float*)d_in[9];
    const int*   brw  = (const int*)d_in[10];
    float* out = (float*)d_out;

    char* ws = (char*)d_ws;
    // layout: [0] ecnt, [64] sums[64], [320] sumsq[64] (pad to 1024),
    // [1024] vmax 2MB, [+2MB] vmin 2MB, then bati 32KB, bstart 64B
    int*   ecnt   = (int*)(ws + 0);
    float* sums   = (float*)(ws + 64);
    float* sumsq  = (float*)(ws + 320);
    float* vmaxg  = (float*)(ws + 1024);
    float* vming  = (float*)(ws + 1024 + 2097152);
    int*   bati   = (int*)(ws + 1024 + 2 * 2097152);
    int*   bstart = (int*)(ws + 1024 + 2 * 2097152 + 32768);

    hipMemsetAsync(ws, 0, 1024, stream);   // ecnt + sums + sumsq only

    k0_setup<<<1, 1024, 0, stream>>>(brw, bati, bstart);
    k12_fused<<<GRID12, 256, 0, stream>>>(xin, pos, rfl, sf, w1, b1, w2, b2,
                                          bati, bstart, vmaxg, vming, sums, sumsq, ecnt);
    k3_fin<<<(O_TOT + 255) / 256, 256, 0, stream>>>(vmaxg, vming, sums, sumsq, gam, bet,
                                                    ecnt, pos, bati, rfl, sf, out);
}